// Round 1
// baseline (535.288 us; speedup 1.0000x reference)
//
#include <hip/hip_runtime.h>

// Transducer joint: out[b,t,u,o] = leaky_relu(tn_proj[b,t,o] + pn_proj[b,u,o] + bias[o])
// Shapes: B=8, T=300, U=80, H=512, O=640.
// tn_proj = (B*T, H) x (H, O) GEMM, pn_proj = (B*U, H) x (H, O) GEMM (second half of W).

#define DIM_H 512
#define DIM_O 640
#define DIM_B 8
#define DIM_T 300
#define DIM_U 80
#define M_TN  2400   // B*T
#define M_PN  640    // B*U
#define NEG_SLOPE 0.01f

#define BK 16
#define NB_N (DIM_O / 64)              // 10 column blocks
#define NB_TN (((M_TN + 63) / 64) * NB_N)  // 38*10 = 380
#define NB_PN (((M_PN + 63) / 64) * NB_N)  // 10*10 = 100

// Fused dual projection GEMM. Blocks [0, NB_TN) compute tn_proj = TN * W[:512];
// blocks [NB_TN, NB_TN+NB_PN) compute pn_proj = PN * W[512:] + bias.
__global__ __launch_bounds__(256, 2) void proj_gemm(
    const float* __restrict__ tn_in,   // M_TN x H
    const float* __restrict__ pn_in,   // M_PN x H
    const float* __restrict__ W,       // (2H) x O row-major
    const float* __restrict__ bias,    // O
    float* __restrict__ tn_out,        // M_TN x O
    float* __restrict__ pn_out)        // M_PN x O
{
    const int bid = blockIdx.x;
    const float* A; const float* Wp; float* Cout; int M; bool addb; int local;
    if (bid < NB_TN) {
        A = tn_in; Wp = W;               Cout = tn_out; M = M_TN; addb = false; local = bid;
    } else {
        A = pn_in; Wp = W + DIM_H * DIM_O; Cout = pn_out; M = M_PN; addb = true;  local = bid - NB_TN;
    }
    const int bm = local / NB_N;
    const int bn = local - bm * NB_N;
    const int row0 = bm * 64;
    const int col0 = bn * 64;

    // As stored transposed: As[kk][row], padded to 68 so the 4-scalar transpose
    // store is ~conflict-free and float4 reads stay 16B-aligned (68*4 = 272 = 17*16).
    __shared__ float As[BK][68];
    __shared__ float Bs[BK][64];

    const int tid = threadIdx.x;
    const int ty = tid >> 4;            // 0..15 -> output rows ty*4..ty*4+3
    const int tx = tid & 15;            // 0..15 -> output cols tx*4..tx*4+3
    const int ar  = tid >> 2;           // A load: row 0..63
    const int ac4 = (tid & 3) << 2;     // A load: k-col group 0/4/8/12
    const int br  = tid >> 4;           // B load: k-row 0..15
    const int bc4 = (tid & 15) << 2;    // B load: col group

    float acc[4][4];
    #pragma unroll
    for (int i = 0; i < 4; ++i)
        #pragma unroll
        for (int j = 0; j < 4; ++j) acc[i][j] = 0.f;

    const int gr = row0 + ar;
    for (int k0 = 0; k0 < DIM_H; k0 += BK) {
        float4 av = make_float4(0.f, 0.f, 0.f, 0.f);
        if (gr < M) av = *(const float4*)(A + (size_t)gr * DIM_H + k0 + ac4);
        const float4 bv = *(const float4*)(Wp + (size_t)(k0 + br) * DIM_O + col0 + bc4);

        __syncthreads();   // previous iteration's reads done before overwrite
        // transpose-store A fragment: As[k][row]
        As[ac4 + 0][ar] = av.x;
        As[ac4 + 1][ar] = av.y;
        As[ac4 + 2][ar] = av.z;
        As[ac4 + 3][ar] = av.w;
        *(float4*)&Bs[br][bc4] = bv;
        __syncthreads();

        #pragma unroll
        for (int kk = 0; kk < BK; ++kk) {
            const float4 a = *(const float4*)&As[kk][ty << 2];
            const float4 b = *(const float4*)&Bs[kk][tx << 2];
            acc[0][0] = fmaf(a.x, b.x, acc[0][0]);
            acc[0][1] = fmaf(a.x, b.y, acc[0][1]);
            acc[0][2] = fmaf(a.x, b.z, acc[0][2]);
            acc[0][3] = fmaf(a.x, b.w, acc[0][3]);
            acc[1][0] = fmaf(a.y, b.x, acc[1][0]);
            acc[1][1] = fmaf(a.y, b.y, acc[1][1]);
            acc[1][2] = fmaf(a.y, b.z, acc[1][2]);
            acc[1][3] = fmaf(a.y, b.w, acc[1][3]);
            acc[2][0] = fmaf(a.z, b.x, acc[2][0]);
            acc[2][1] = fmaf(a.z, b.y, acc[2][1]);
            acc[2][2] = fmaf(a.z, b.z, acc[2][2]);
            acc[2][3] = fmaf(a.z, b.w, acc[2][3]);
            acc[3][0] = fmaf(a.w, b.x, acc[3][0]);
            acc[3][1] = fmaf(a.w, b.y, acc[3][1]);
            acc[3][2] = fmaf(a.w, b.z, acc[3][2]);
            acc[3][3] = fmaf(a.w, b.w, acc[3][3]);
        }
    }

    // Epilogue: optional bias add (pn path), float4 stores.
    float4 bsv = make_float4(0.f, 0.f, 0.f, 0.f);
    if (addb) bsv = *(const float4*)(bias + col0 + (tx << 2));
    #pragma unroll
    for (int i = 0; i < 4; ++i) {
        const int r = row0 + (ty << 2) + i;
        if (r < M) {
            float4 v;
            v.x = acc[i][0] + bsv.x;
            v.y = acc[i][1] + bsv.y;
            v.z = acc[i][2] + bsv.z;
            v.w = acc[i][3] + bsv.w;
            *(float4*)(Cout + (size_t)r * DIM_O + col0 + (tx << 2)) = v;
        }
    }
}

// Broadcast + leaky_relu. One block per (b,t) row. tn row staged in LDS; pn rows
// served from L2 (each batch's 205 KB pn panel is reused by 300 blocks).
__global__ __launch_bounds__(256) void joint_kernel(
    const float* __restrict__ tn_proj,   // M_TN x O
    const float* __restrict__ pn_proj,   // M_PN x O (bias pre-added)
    float* __restrict__ out)             // [bt][u][o]
{
    const int bt = blockIdx.x;           // 0..2399
    const int b = bt / DIM_T;
    const int tid = threadIdx.x;

    __shared__ float4 tns[DIM_O / 4];    // 160 float4 = 2.56 KB
    if (tid < DIM_O / 4)
        tns[tid] = ((const float4*)(tn_proj + (size_t)bt * DIM_O))[tid];
    __syncthreads();

    const float4* __restrict__ pn4 = (const float4*)(pn_proj + (size_t)b * DIM_U * DIM_O);
    float4* __restrict__ out4 = (float4*)(out + (size_t)bt * DIM_U * DIM_O);

    const int total = DIM_U * (DIM_O / 4);   // 12800 -> exactly 50 iters/thread
    for (int idx = tid; idx < total; idx += 256) {
        const int u = idx / (DIM_O / 4);
        const int o4 = idx - u * (DIM_O / 4);
        const float4 t = tns[o4];
        const float4 p = pn4[idx];
        float4 r;
        r.x = t.x + p.x;
        r.y = t.y + p.y;
        r.z = t.z + p.z;
        r.w = t.w + p.w;
        r.x = fmaxf(r.x, 0.f) + NEG_SLOPE * fminf(r.x, 0.f);
        r.y = fmaxf(r.y, 0.f) + NEG_SLOPE * fminf(r.y, 0.f);
        r.z = fmaxf(r.z, 0.f) + NEG_SLOPE * fminf(r.z, 0.f);
        r.w = fmaxf(r.w, 0.f) + NEG_SLOPE * fminf(r.w, 0.f);
        out4[idx] = r;
    }
}

extern "C" void kernel_launch(void* const* d_in, const int* in_sizes, int n_in,
                              void* d_out, int out_size, void* d_ws, size_t ws_size,
                              hipStream_t stream) {
    const float* tn   = (const float*)d_in[0];   // (8,300,1,512)
    const float* pn   = (const float*)d_in[1];   // (8,1,80,512)
    const float* W    = (const float*)d_in[2];   // (1024,640)
    const float* bias = (const float*)d_in[3];   // (640,)
    float* out = (float*)d_out;

    float* tn_proj = (float*)d_ws;                       // 2400*640 fp32 = 6.14 MB
    float* pn_proj = tn_proj + (size_t)M_TN * DIM_O;     // 640*640 fp32 = 1.64 MB

    proj_gemm<<<NB_TN + NB_PN, 256, 0, stream>>>(tn, pn, W, bias, tn_proj, pn_proj);
    joint_kernel<<<M_TN, 256, 0, stream>>>(tn_proj, pn_proj, out);
}

// Round 6
// 522.560 us; speedup vs baseline: 1.0244x; 1.0244x over previous
//
#include <hip/hip_runtime.h>

// Transducer joint: out[b,t,u,o] = leaky_relu(tn_proj[b,t,o] + pn_proj[b,u,o] + bias[o])
// Shapes: B=8, T=300, U=80, H=512, O=640.
// Stage 1: fused dual GEMM -> tn_proj (2400x640), pn_proj (640x640, bias folded).
// Stage 2: broadcast add + leaky_relu, write-bound (491.5 MB, floor ~79 us @6.25 TB/s).

#define DIM_H 512
#define DIM_O 640
#define DIM_B 8
#define DIM_T 300
#define DIM_U 80
#define M_TN  2400   // B*T
#define M_PN  640    // B*U
#define NEG_SLOPE 0.01f

#define BK 32
#define NB_N (DIM_O / 64)                  // 10 column blocks
#define NB_TN (((M_TN + 63) / 64) * NB_N)  // 38*10 = 380
#define NB_PN (((M_PN + 63) / 64) * NB_N)  // 10*10 = 100

typedef float f32x4 __attribute__((ext_vector_type(4)));

// Fused dual projection GEMM. Blocks [0, NB_TN): tn_proj = TN * W[:512].
// Blocks [NB_TN, NB_TN+NB_PN): pn_proj = PN * W[512:] + bias.
// 64x64 tile, BK=32, software-prefetched global loads (next tile issued
// before the compute phase so ~600cy VMEM latency hides under 32kk of FMA).
__global__ __launch_bounds__(256, 2) void proj_gemm(
    const float* __restrict__ tn_in,
    const float* __restrict__ pn_in,
    const float* __restrict__ W,
    const float* __restrict__ bias,
    float* __restrict__ tn_out,
    float* __restrict__ pn_out)
{
    const int bid = blockIdx.x;
    const float* A; const float* Wp; float* Cout; int M; bool addb; int local;
    if (bid < NB_TN) {
        A = tn_in; Wp = W;                 Cout = tn_out; M = M_TN; addb = false; local = bid;
    } else {
        A = pn_in; Wp = W + DIM_H * DIM_O; Cout = pn_out; M = M_PN; addb = true;  local = bid - NB_TN;
    }
    const int bm = local / NB_N;
    const int bn = local - bm * NB_N;
    const int row0 = bm * 64;
    const int col0 = bn * 64;

    // As transposed: As[kk][row], pad 68 keeps the scalar transpose-store at
    // worst 2-way bank aliased (free per m136) and float4 reads 16B-aligned.
    __shared__ float As[BK][68];
    __shared__ float Bs[BK][64];

    const int tid = threadIdx.x;
    const int ty = tid >> 4;             // output rows ty*4..+3
    const int tx = tid & 15;             // output cols tx*4..+3
    const int ar = tid >> 2;             // A load row 0..63
    const int ac = (tid & 3) << 3;       // A load k-offset 0/8/16/24
    const int br = tid >> 3;             // B load k-row 0..31
    const int bc = (tid & 7) << 3;       // B load col-offset

    float acc[4][4];
    #pragma unroll
    for (int i = 0; i < 4; ++i)
        #pragma unroll
        for (int j = 0; j < 4; ++j) acc[i][j] = 0.f;

    const int gr = row0 + ar;
    const bool arow_ok = (gr < M);
    const float* __restrict__ Arow = A + (size_t)gr * DIM_H;
    const float* __restrict__ Bbase = Wp + col0;

    f32x4 a0 = 0.f, a1 = 0.f, b0, b1;
    if (arow_ok) {
        a0 = *(const f32x4*)(Arow + ac);
        a1 = *(const f32x4*)(Arow + ac + 4);
    }
    b0 = *(const f32x4*)(Bbase + (size_t)br * DIM_O + bc);
    b1 = *(const f32x4*)(Bbase + (size_t)br * DIM_O + bc + 4);

    for (int k0 = 0; k0 < DIM_H; k0 += BK) {
        __syncthreads();   // previous compute done reading LDS
        #pragma unroll
        for (int j = 0; j < 4; ++j) {
            As[ac + j][ar]     = a0[j];
            As[ac + 4 + j][ar] = a1[j];
        }
        *(f32x4*)&Bs[br][bc]     = b0;
        *(f32x4*)&Bs[br][bc + 4] = b1;
        __syncthreads();

        const int kn = k0 + BK;
        if (kn < DIM_H) {   // prefetch next tile; latency hides under compute
            if (arow_ok) {
                a0 = *(const f32x4*)(Arow + kn + ac);
                a1 = *(const f32x4*)(Arow + kn + ac + 4);
            }
            b0 = *(const f32x4*)(Bbase + (size_t)(kn + br) * DIM_O + bc);
            b1 = *(const f32x4*)(Bbase + (size_t)(kn + br) * DIM_O + bc + 4);
        }

        #pragma unroll
        for (int kk = 0; kk < BK; ++kk) {
            const f32x4 a = *(const f32x4*)&As[kk][ty << 2];
            const f32x4 b = *(const f32x4*)&Bs[kk][tx << 2];
            #pragma unroll
            for (int i = 0; i < 4; ++i) {
                acc[i][0] = fmaf(a[i], b[0], acc[i][0]);
                acc[i][1] = fmaf(a[i], b[1], acc[i][1]);
                acc[i][2] = fmaf(a[i], b[2], acc[i][2]);
                acc[i][3] = fmaf(a[i], b[3], acc[i][3]);
            }
        }
    }

    f32x4 bsv = 0.f;
    if (addb) bsv = *(const f32x4*)(bias + col0 + (tx << 2));
    #pragma unroll
    for (int i = 0; i < 4; ++i) {
        const int r = row0 + (ty << 2) + i;
        if (r < M) {
            f32x4 v;
            #pragma unroll
            for (int j = 0; j < 4; ++j) v[j] = acc[i][j] + bsv[j];
            *(f32x4*)(Cout + (size_t)r * DIM_O + col0 + (tx << 2)) = v;
        }
    }
}

// Broadcast + leaky_relu. One block per (b,t) row, 640 threads.
// Thread owns a fixed output column group o4 = tid%160; tn value lives in a
// register; u strided by 4 -> idx += 640, zero per-iter index math, 20 iters.
// Output stores are nontemporal: 491.5 MB of streaming writes must not evict
// the pn panels (1.64 MB, re-read by every block) from L2.
__global__ __launch_bounds__(640) void joint_kernel(
    const float* __restrict__ tn_proj,   // M_TN x O
    const float* __restrict__ pn_proj,   // M_PN x O (bias pre-added)
    float* __restrict__ out)             // [bt][u][o]
{
    const int bt = blockIdx.x;           // 0..2399
    const int b = bt / DIM_T;
    const int tid = threadIdx.x;

    __shared__ f32x4 tns[DIM_O / 4];     // 160 f32x4 = 2.56 KB
    if (tid < DIM_O / 4)
        tns[tid] = ((const f32x4*)(tn_proj + (size_t)bt * DIM_O))[tid];
    __syncthreads();

    const int o4 = tid % (DIM_O / 4);    // fixed column group per thread
    const f32x4 t = tns[o4];

    const f32x4* __restrict__ pn4 = (const f32x4*)(pn_proj + (size_t)b * DIM_U * DIM_O);
    f32x4* __restrict__ out4 = (f32x4*)(out + (size_t)bt * DIM_U * DIM_O);

    #pragma unroll 4
    for (int idx = tid; idx < DIM_U * (DIM_O / 4); idx += 640) {
        const f32x4 p = pn4[idx];
        f32x4 r;
        #pragma unroll
        for (int j = 0; j < 4; ++j) {
            const float x = t[j] + p[j];
            r[j] = fmaxf(x, 0.f) + NEG_SLOPE * fminf(x, 0.f);
        }
        __builtin_nontemporal_store(r, &out4[idx]);
    }
}

extern "C" void kernel_launch(void* const* d_in, const int* in_sizes, int n_in,
                              void* d_out, int out_size, void* d_ws, size_t ws_size,
                              hipStream_t stream) {
    const float* tn   = (const float*)d_in[0];   // (8,300,1,512)
    const float* pn   = (const float*)d_in[1];   // (8,1,80,512)
    const float* W    = (const float*)d_in[2];   // (1024,640)
    const float* bias = (const float*)d_in[3];   // (640,)
    float* out = (float*)d_out;

    float* tn_proj = (float*)d_ws;                       // 2400*640 fp32 = 6.14 MB
    float* pn_proj = tn_proj + (size_t)M_TN * DIM_O;     // 640*640 fp32 = 1.64 MB

    proj_gemm<<<NB_TN + NB_PN, 256, 0, stream>>>(tn, pn, W, bias, tn_proj, pn_proj);
    joint_kernel<<<M_TN, 640, 0, stream>>>(tn_proj, pn_proj, out);
}